// Round 2
// baseline (527.621 us; speedup 1.0000x reference)
//
#include <hip/hip_runtime.h>
#include <hip/hip_bf16.h>

typedef __bf16 bf16_t;
typedef __bf16 bf16x4_t __attribute__((ext_vector_type(4)));
typedef __bf16 bf16x8_t __attribute__((ext_vector_type(8)));
typedef float f32x4_t __attribute__((ext_vector_type(4)));

#define NROWS 8192
#define DDIM  256
#define HDIM  512

#define MFMA16(a, b, c) __builtin_amdgcn_mfma_f32_16x16x32_bf16((a), (b), (c), 0, 0, 0)

// ---------------------------------------------------------------------------
// prep_x: round X to bf16, compute sq[i] = sum_k bf16(x[i,k])^2 (f32 accum).
// sq MUST come from the bf16-rounded values so the diagonal d2 cancels ~exactly
// (otherwise K[i,i] != 1 and the result is badly wrong).
// Also zeroes the two loss accumulators.
// ---------------------------------------------------------------------------
__global__ __launch_bounds__(256) void prep_x_kernel(
    const float* __restrict__ x, bf16_t* __restrict__ xb,
    float* __restrict__ sq, float* __restrict__ partials)
{
    const int row  = (blockIdx.x << 2) + (threadIdx.x >> 6); // one wave per row
    const int lane = threadIdx.x & 63;
    float4 v = *reinterpret_cast<const float4*>(x + row * DDIM + (lane << 2));
    bf16x4_t b;
    b[0] = (bf16_t)v.x; b[1] = (bf16_t)v.y; b[2] = (bf16_t)v.z; b[3] = (bf16_t)v.w;
    *reinterpret_cast<bf16x4_t*>(xb + row * DDIM + (lane << 2)) = b;
    float f0 = (float)b[0], f1 = (float)b[1], f2 = (float)b[2], f3 = (float)b[3];
    float ss = f0 * f0 + f1 * f1 + f2 * f2 + f3 * f3;
    #pragma unroll
    for (int m = 32; m > 0; m >>= 1) ss += __shfl_xor(ss, m, 64);
    if (lane == 0) sq[row] = ss;
    if (blockIdx.x == 0 && threadIdx.x == 0) { partials[0] = 0.f; partials[1] = 0.f; }
}

// ---------------------------------------------------------------------------
// prep_h: H [8192][512] f32  ->  Hbt [512][8192] bf16 (transposed), via LDS tile.
// Gives the O-GEMM B-operand 16B-contiguous per-lane loads.
// ---------------------------------------------------------------------------
__global__ __launch_bounds__(256) void prep_h_kernel(
    const float* __restrict__ h, bf16_t* __restrict__ hbt)
{
    __shared__ float tile[32][33];
    const int bi = blockIdx.x & 255;  // i-tile (8192/32)
    const int bh = blockIdx.x >> 8;   // h-tile (512/32)
    const int i0 = bi << 5, h0 = bh << 5;
    const int c  = threadIdx.x & 31;
    const int rt = threadIdx.x >> 5;  // 0..7
    #pragma unroll
    for (int k = 0; k < 4; ++k) {
        int r = rt + (k << 3);
        tile[r][c] = h[(size_t)(i0 + r) * HDIM + h0 + c];
    }
    __syncthreads();
    #pragma unroll
    for (int k = 0; k < 4; ++k) {
        int hr = rt + (k << 3);
        hbt[(size_t)(h0 + hr) * NROWS + i0 + c] = (bf16_t)tile[c][hr];
    }
}

// ---------------------------------------------------------------------------
// Main fused kernel. Grid = 256 blocks (one 32-row j-tile each), 512 threads
// (8 waves). Wave w: S-fragment (m = w&1, isub = w>>1); O h-slice [w*64,w*64+64).
// Per i-chunk (64):
//   preload hv (Hbt B-frags, independent of P -> latency hides under S)
//   S = Xj(32x256) @ Xi(64x256)^T    (MFMA; A-frags hoisted, loop-invariant)
//   P = exp2(-max(sqj+sqi-2S,0)*log2e) -> bf16 -> LDS[buf] (XOR-swizzled)
//   ONE barrier (double-buffered P)
//   O += P(32x64) @ Hbt-slice        (A from LDS, B preloaded)
// Epilogue: p1 = sum invlam[h]*O^2, p2 = sum O*H -> LDS-reduce -> 2 atomics.
// ---------------------------------------------------------------------------
__global__ __launch_bounds__(512, 2) void kpca_main(
    const bf16_t* __restrict__ xb, const bf16_t* __restrict__ hbt,
    const float* __restrict__ sq, const float* __restrict__ hmat,
    const float* __restrict__ invlam, float* __restrict__ partials)
{
    __shared__ bf16_t plds[2][32 * 64];
    __shared__ float red[32];

    const int tid  = threadIdx.x;
    const int w    = tid >> 6;       // wave 0..7
    const int l    = tid & 63;
    const int l15  = l & 15;
    const int lq   = l >> 4;         // 0..3
    const int j0   = blockIdx.x << 5;
    const int m    = w & 1;          // S-phase m-frag
    const int isub = w >> 1;         // S-phase i-sub (0..3)
    const int h0w  = w << 6;         // wave's h base

    f32x4_t acc[2][4];
    #pragma unroll
    for (int a = 0; a < 2; ++a)
        #pragma unroll
        for (int b = 0; b < 4; ++b)
            acc[a][b] = (f32x4_t){0.f, 0.f, 0.f, 0.f};

    // Hoisted S-phase A fragments: row j0+m*16+l15, k = kk*32 + lq*8 (+0..8)
    bf16x8_t av[8];
    {
        const bf16_t* aptr = xb + (size_t)(j0 + (m << 4) + l15) * DDIM + (lq << 3);
        #pragma unroll
        for (int kk = 0; kk < 8; ++kk)
            av[kk] = *reinterpret_cast<const bf16x8_t*>(aptr + (kk << 5));
    }
    // sqj for the P fragment rows (fixed per lane)
    float sqj[4];
    #pragma unroll
    for (int r = 0; r < 4; ++r) sqj[r] = sq[j0 + (m << 4) + (lq << 2) + r];
    // O-phase B operand base: Hbt[h0w + nf*16 + l15][lq*8 + ...]
    const bf16_t* hbase = hbt + (size_t)(h0w + l15) * NROWS + (lq << 3);

    int buf = 0;
    for (int ic = 0; ic < NROWS; ic += 64) {
        // ---- preload O-phase B fragments (independent of P) ----
        bf16x8_t hv[2][4];
        #pragma unroll
        for (int kf = 0; kf < 2; ++kf)
            #pragma unroll
            for (int nf = 0; nf < 4; ++nf)
                hv[kf][nf] = *reinterpret_cast<const bf16x8_t*>(
                    hbase + (size_t)nf * (16 * NROWS) + ic + (kf << 5));

        // ---- S-GEMM: one 16x16 fragment per wave, K=256, 2 chains ----
        const bf16_t* bptr = xb + (size_t)(ic + (isub << 4) + l15) * DDIM + (lq << 3);
        f32x4_t s0 = (f32x4_t){0.f, 0.f, 0.f, 0.f};
        f32x4_t s1 = (f32x4_t){0.f, 0.f, 0.f, 0.f};
        #pragma unroll
        for (int kk = 0; kk < 8; kk += 2) {
            bf16x8_t bv0 = *reinterpret_cast<const bf16x8_t*>(bptr + (kk << 5));
            bf16x8_t bv1 = *reinterpret_cast<const bf16x8_t*>(bptr + ((kk + 1) << 5));
            s0 = MFMA16(av[kk], bv0, s0);
            s1 = MFMA16(av[kk + 1], bv1, s1);
        }

        // ---- P = exp(-d2/2), write bf16 to swizzled LDS[buf] ----
        const float sqi = sq[ic + (isub << 4) + l15];
        #pragma unroll
        for (int r = 0; r < 4; ++r) {
            float sv = s0[r] + s1[r];
            float d2 = fmaxf(sqj[r] + sqi - 2.0f * sv, 0.0f);
            float p  = exp2f(d2 * -0.721347520444482f); // = exp(-d2/2)
            int jl = (m << 4) + (lq << 2) + r;
            int il = (isub << 4) + l15;
            plds[buf][(jl << 6) + (il ^ ((jl & 7) << 3))] = (bf16_t)p;
        }
        __syncthreads();

        // ---- O-GEMM: O[32][64 h] += P[32][64 i] @ Hbt-slice ----
        #pragma unroll
        for (int kf = 0; kf < 2; ++kf) {
            bf16x8_t pa[2];
            #pragma unroll
            for (int mf = 0; mf < 2; ++mf) {
                int jl = (mf << 4) + l15;
                int ik = (kf << 5) + (lq << 3);
                pa[mf] = *reinterpret_cast<const bf16x8_t*>(
                    &plds[buf][(jl << 6) + (ik ^ ((jl & 7) << 3))]);
            }
            #pragma unroll
            for (int nf = 0; nf < 4; ++nf) {
                acc[0][nf] = MFMA16(pa[0], hv[kf][nf], acc[0][nf]);
                acc[1][nf] = MFMA16(pa[1], hv[kf][nf], acc[1][nf]);
            }
        }
        buf ^= 1;
    }

    // ---- epilogue: loss partials ----
    float p1 = 0.f, p2 = 0.f;
    #pragma unroll
    for (int mf = 0; mf < 2; ++mf) {
        #pragma unroll
        for (int nf = 0; nf < 4; ++nf) {
            const int hh = h0w + (nf << 4) + l15;
            const float lam = invlam[hh];
            #pragma unroll
            for (int r = 0; r < 4; ++r) {
                const int j = j0 + (mf << 4) + (lq << 2) + r;
                const float v = acc[mf][nf][r];
                p1 = fmaf(lam * v, v, p1);
                p2 = fmaf(v, hmat[(size_t)j * HDIM + hh], p2);
            }
        }
    }
    #pragma unroll
    for (int sft = 32; sft > 0; sft >>= 1) {
        p1 += __shfl_xor(p1, sft, 64);
        p2 += __shfl_xor(p2, sft, 64);
    }
    if (l == 0) { red[w] = p1; red[16 + w] = p2; }
    __syncthreads();
    if (tid == 0) {
        float a = 0.f, b = 0.f;
        #pragma unroll
        for (int i = 0; i < 8; ++i) { a += red[i]; b += red[16 + i]; }
        atomicAdd(&partials[0], a);
        atomicAdd(&partials[1], b);
    }
}

// ---------------------------------------------------------------------------
// finalize: s = loss1 + loss2, out = s + 0.05*s^2
// ---------------------------------------------------------------------------
__global__ void finalize_kernel(const float* __restrict__ partials,
                                float* __restrict__ out)
{
    if (threadIdx.x == 0) {
        float s = -0.5f * partials[0] + 0.5f * partials[1];
        out[0] = s + 0.05f * s * s;
    }
}

// ---------------------------------------------------------------------------
// ws layout: Xb bf16[8192][256] (4MB) | Hbt bf16[512][8192] (8MB)
//            | sq f32[8192] (32KB) | partials f32[2]        (~12.03 MB total)
// ---------------------------------------------------------------------------
extern "C" void kernel_launch(void* const* d_in, const int* in_sizes, int n_in,
                              void* d_out, int out_size, void* d_ws, size_t ws_size,
                              hipStream_t stream)
{
    const float* x      = (const float*)d_in[0];
    const float* h      = (const float*)d_in[1];
    const float* invlam = (const float*)d_in[2];
    float* out = (float*)d_out;

    char* wsb = (char*)d_ws;
    bf16_t* xb  = (bf16_t*)wsb;
    bf16_t* hbt = (bf16_t*)(wsb + (size_t)NROWS * DDIM * 2);
    float*  sq  = (float*)(wsb + (size_t)NROWS * DDIM * 2 + (size_t)HDIM * NROWS * 2);
    float*  partials = sq + NROWS;

    hipLaunchKernelGGL(prep_x_kernel, dim3(NROWS / 4), dim3(256), 0, stream,
                       x, xb, sq, partials);
    hipLaunchKernelGGL(prep_h_kernel, dim3((NROWS / 32) * (HDIM / 32)), dim3(256), 0, stream,
                       h, hbt);
    hipLaunchKernelGGL(kpca_main, dim3(NROWS / 32), dim3(512), 0, stream,
                       xb, hbt, sq, h, invlam, partials);
    hipLaunchKernelGGL(finalize_kernel, dim3(1), dim3(64), 0, stream,
                       partials, out);
}

// Round 4
// 312.671 us; speedup vs baseline: 1.6875x; 1.6875x over previous
//
#include <hip/hip_runtime.h>
#include <hip/hip_bf16.h>

typedef __bf16 bf16_t;
typedef __bf16 bf16x4_t __attribute__((ext_vector_type(4)));
typedef __bf16 bf16x8_t __attribute__((ext_vector_type(8)));
typedef float f32x4_t __attribute__((ext_vector_type(4)));

#define NROWS 8192
#define DDIM  256
#define HDIM  512

#define MFMA16(a, b, c) __builtin_amdgcn_mfma_f32_16x16x32_bf16((a), (b), (c), 0, 0, 0)

// ---------------------------------------------------------------------------
// prep_x: round X to bf16, compute sq[i] = sum_k bf16(x[i,k])^2 (f32 accum).
// sq MUST come from the bf16-rounded values so the diagonal d2 cancels exactly
// (K[i,i] = exp(0) = 1). Also zeroes the loss accumulators.
// ---------------------------------------------------------------------------
__global__ __launch_bounds__(256) void prep_x_kernel(
    const float* __restrict__ x, bf16_t* __restrict__ xb,
    float* __restrict__ sq, float* __restrict__ partials)
{
    const int row  = (blockIdx.x << 2) + (threadIdx.x >> 6); // one wave per row
    const int lane = threadIdx.x & 63;
    float4 v = *reinterpret_cast<const float4*>(x + row * DDIM + (lane << 2));
    bf16x4_t b;
    b[0] = (bf16_t)v.x; b[1] = (bf16_t)v.y; b[2] = (bf16_t)v.z; b[3] = (bf16_t)v.w;
    *reinterpret_cast<bf16x4_t*>(xb + row * DDIM + (lane << 2)) = b;
    float f0 = (float)b[0], f1 = (float)b[1], f2 = (float)b[2], f3 = (float)b[3];
    float ss = f0 * f0 + f1 * f1 + f2 * f2 + f3 * f3;
    #pragma unroll
    for (int m = 32; m > 0; m >>= 1) ss += __shfl_xor(ss, m, 64);
    if (lane == 0) sq[row] = ss;
    if (blockIdx.x == 0 && threadIdx.x == 0) { partials[0] = 0.f; partials[1] = 0.f; }
}

// ---------------------------------------------------------------------------
// prep_h: H [8192][512] f32 -> Hbt [512][8192] bf16 (transposed), via LDS tile.
// ---------------------------------------------------------------------------
__global__ __launch_bounds__(256) void prep_h_kernel(
    const float* __restrict__ h, bf16_t* __restrict__ hbt)
{
    __shared__ float tile[32][33];
    const int bi = blockIdx.x & 255;  // i-tile (8192/32)
    const int bh = blockIdx.x >> 8;   // h-tile (512/32)
    const int i0 = bi << 5, h0 = bh << 5;
    const int c  = threadIdx.x & 31;
    const int rt = threadIdx.x >> 5;  // 0..7
    #pragma unroll
    for (int k = 0; k < 4; ++k) {
        int r = rt + (k << 3);
        tile[r][c] = h[(size_t)(i0 + r) * HDIM + h0 + c];
    }
    __syncthreads();
    #pragma unroll
    for (int k = 0; k < 4; ++k) {
        int hr = rt + (k << 3);
        hbt[(size_t)(h0 + hr) * NROWS + i0 + c] = (bf16_t)tile[c][hr];
    }
}

// ---------------------------------------------------------------------------
// Main fused kernel. Grid = 256 blocks (32-row j-tile each), 512 threads
// (8 waves). Wave w: S-fragment (m = w&1, isub = w>>1); O h-slice [w*64,+64).
// Per 64-i chunk:
//   S = Xj(32x256) @ Xi(64x256)^T   (MFMA; A-frags hoisted; B-frags register-
//                                    prefetched 2 chunks deep -> L2 latency hidden)
//   P = exp2(-max(sqj+sqi-2S,0)*log2e/2) -> bf16 -> LDS[buf] (XOR-swizzled)
//   block-wide vote: if ALL P values are exactly +0.0 (true for every
//   off-diagonal chunk of this dataset: d2/2 ~ 256 >> underflow threshold),
//   SKIP the O-GEMM and its Hbt loads entirely. Contribution of skipped
//   MFMAs is exactly +0.0 -> output bit-identical to the non-skipping kernel.
//   ONE barrier per chunk (double-buffered P + flags).
// Epilogue: p1 = sum invlam[h]*O^2, p2 = sum O*H -> LDS-reduce -> 2 atomics.
// ---------------------------------------------------------------------------
__global__ __launch_bounds__(512, 2) void kpca_main(
    const bf16_t* __restrict__ xb, const bf16_t* __restrict__ hbt,
    const float* __restrict__ sq, const float* __restrict__ hmat,
    const float* __restrict__ invlam, float* __restrict__ partials)
{
    __shared__ bf16_t plds[2][32 * 64];
    __shared__ unsigned long long flagsq[2];
    __shared__ float red[32];

    const int tid  = threadIdx.x;
    const int w    = tid >> 6;       // wave 0..7
    const int l    = tid & 63;
    const int l15  = l & 15;
    const int lq   = l >> 4;         // 0..3
    const int j0   = blockIdx.x << 5;
    const int m    = w & 1;          // S-phase m-frag
    const int isub = w >> 1;         // S-phase i-sub (0..3)
    const int h0w  = w << 6;         // wave's h base

    f32x4_t acc[2][4];
    #pragma unroll
    for (int a = 0; a < 2; ++a)
        #pragma unroll
        for (int b = 0; b < 4; ++b)
            acc[a][b] = (f32x4_t){0.f, 0.f, 0.f, 0.f};

    // Hoisted S-phase A fragments (loop-invariant): row j0+m*16+l15
    bf16x8_t av[8];
    {
        const bf16_t* aptr = xb + (size_t)(j0 + (m << 4) + l15) * DDIM + (lq << 3);
        #pragma unroll
        for (int kk = 0; kk < 8; ++kk)
            av[kk] = *reinterpret_cast<const bf16x8_t*>(aptr + (kk << 5));
    }
    float sqj[4];
    #pragma unroll
    for (int r = 0; r < 4; ++r) sqj[r] = sq[j0 + (m << 4) + (lq << 2) + r];
    const bf16_t* hbase = hbt + (size_t)(h0w + l15) * NROWS + (lq << 3);

    // chunk body: S-MFMA on prefetched B-frags, P+vote, conditional O-GEMM
    auto chunk_body = [&](int ic, const bf16x8_t (&bvc)[8], int buf) {
        f32x4_t s0 = (f32x4_t){0.f, 0.f, 0.f, 0.f};
        f32x4_t s1 = (f32x4_t){0.f, 0.f, 0.f, 0.f};
        #pragma unroll
        for (int kk = 0; kk < 8; kk += 2) {
            s0 = MFMA16(av[kk],     bvc[kk],     s0);
            s1 = MFMA16(av[kk + 1], bvc[kk + 1], s1);
        }
        const float sqi = sq[ic + (isub << 4) + l15];
        float pmax = 0.f;
        #pragma unroll
        for (int r = 0; r < 4; ++r) {
            float sv = s0[r] + s1[r];
            float d2 = fmaxf(sqj[r] + sqi - 2.0f * sv, 0.0f);
            float p  = exp2f(d2 * -0.721347520444482f); // = exp(-d2/2)
            pmax = fmaxf(pmax, p);
            int jl = (m << 4) + (lq << 2) + r;
            int il = (isub << 4) + l15;
            plds[buf][(jl << 6) + (il ^ ((jl & 7) << 3))] = (bf16_t)p;
        }
        if (l == 0)
            reinterpret_cast<unsigned char*>(&flagsq[buf])[w] =
                __any(pmax != 0.0f) ? 1 : 0;
        __syncthreads();
        if (flagsq[buf]) {  // any nonzero P in the 32x64 tile -> do O-GEMM
            #pragma unroll
            for (int kf = 0; kf < 2; ++kf) {
                bf16x8_t pa[2];
                #pragma unroll
                for (int mf = 0; mf < 2; ++mf) {
                    int jl = (mf << 4) + l15;
                    int ik = (kf << 5) + (lq << 3);
                    pa[mf] = *reinterpret_cast<const bf16x8_t*>(
                        &plds[buf][(jl << 6) + (ik ^ ((jl & 7) << 3))]);
                }
                #pragma unroll
                for (int nf = 0; nf < 4; ++nf) {
                    bf16x8_t hv = *reinterpret_cast<const bf16x8_t*>(
                        hbase + (size_t)nf * (16 * NROWS) + ic + (kf << 5));
                    acc[0][nf] = MFMA16(pa[0], hv, acc[0][nf]);
                    acc[1][nf] = MFMA16(pa[1], hv, acc[1][nf]);
                }
            }
        }
    };

    auto bptr_at = [&](int ic) {
        return xb + (size_t)(ic + (isub << 4) + l15) * DDIM + (lq << 3);
    };

    // 2-chunk software pipeline on the S B-operand (the dominant stream)
    bf16x8_t bvA[8], bvB[8];
    {
        const bf16_t* p0 = bptr_at(0);
        #pragma unroll
        for (int kk = 0; kk < 8; ++kk)
            bvA[kk] = *reinterpret_cast<const bf16x8_t*>(p0 + (kk << 5));
    }
    for (int ic = 0; ic < NROWS; ic += 128) {
        const bf16_t* pB = bptr_at(ic + 64);
        #pragma unroll
        for (int kk = 0; kk < 8; ++kk)
            bvB[kk] = *reinterpret_cast<const bf16x8_t*>(pB + (kk << 5));
        chunk_body(ic, bvA, 0);
        const bf16_t* pA = bptr_at((ic + 128) & (NROWS - 1)); // wrap: harmless
        #pragma unroll
        for (int kk = 0; kk < 8; ++kk)
            bvA[kk] = *reinterpret_cast<const bf16x8_t*>(pA + (kk << 5));
        chunk_body(ic + 64, bvB, 1);
    }

    // ---- epilogue: loss partials ----
    float p1 = 0.f, p2 = 0.f;
    #pragma unroll
    for (int mf = 0; mf < 2; ++mf) {
        #pragma unroll
        for (int nf = 0; nf < 4; ++nf) {
            const int hh = h0w + (nf << 4) + l15;
            const float lam = invlam[hh];
            #pragma unroll
            for (int r = 0; r < 4; ++r) {
                const int j = j0 + (mf << 4) + (lq << 2) + r;
                const float v = acc[mf][nf][r];
                p1 = fmaf(lam * v, v, p1);
                p2 = fmaf(v, hmat[(size_t)j * HDIM + hh], p2);
            }
        }
    }
    #pragma unroll
    for (int sft = 32; sft > 0; sft >>= 1) {
        p1 += __shfl_xor(p1, sft, 64);
        p2 += __shfl_xor(p2, sft, 64);
    }
    if (l == 0) { red[w] = p1; red[16 + w] = p2; }
    __syncthreads();
    if (tid == 0) {
        float a = 0.f, b = 0.f;
        #pragma unroll
        for (int i = 0; i < 8; ++i) { a += red[i]; b += red[16 + i]; }
        atomicAdd(&partials[0], a);
        atomicAdd(&partials[1], b);
    }
}

// ---------------------------------------------------------------------------
// finalize: s = loss1 + loss2, out = s + 0.05*s^2
// ---------------------------------------------------------------------------
__global__ void finalize_kernel(const float* __restrict__ partials,
                                float* __restrict__ out)
{
    if (threadIdx.x == 0) {
        float s = -0.5f * partials[0] + 0.5f * partials[1];
        out[0] = s + 0.05f * s * s;
    }
}

// ---------------------------------------------------------------------------
// ws layout: Xb bf16[8192][256] (4MB) | Hbt bf16[512][8192] (8MB)
//            | sq f32[8192] (32KB) | partials f32[2]        (~12.03 MB total)
// ---------------------------------------------------------------------------
extern "C" void kernel_launch(void* const* d_in, const int* in_sizes, int n_in,
                              void* d_out, int out_size, void* d_ws, size_t ws_size,
                              hipStream_t stream)
{
    const float* x      = (const float*)d_in[0];
    const float* h      = (const float*)d_in[1];
    const float* invlam = (const float*)d_in[2];
    float* out = (float*)d_out;

    char* wsb = (char*)d_ws;
    bf16_t* xb  = (bf16_t*)wsb;
    bf16_t* hbt = (bf16_t*)(wsb + (size_t)NROWS * DDIM * 2);
    float*  sq  = (float*)(wsb + (size_t)NROWS * DDIM * 2 + (size_t)HDIM * NROWS * 2);
    float*  partials = sq + NROWS;

    hipLaunchKernelGGL(prep_x_kernel, dim3(NROWS / 4), dim3(256), 0, stream,
                       x, xb, sq, partials);
    hipLaunchKernelGGL(prep_h_kernel, dim3((NROWS / 32) * (HDIM / 32)), dim3(256), 0, stream,
                       h, hbt);
    hipLaunchKernelGGL(kpca_main, dim3(NROWS / 32), dim3(512), 0, stream,
                       xb, hbt, sq, h, invlam, partials);
    hipLaunchKernelGGL(finalize_kernel, dim3(1), dim3(64), 0, stream,
                       partials, out);
}

// Round 5
// 206.845 us; speedup vs baseline: 2.5508x; 1.5116x over previous
//
#include <hip/hip_runtime.h>
#include <hip/hip_bf16.h>

typedef __bf16 bf16_t;
typedef __bf16 bf16x4_t __attribute__((ext_vector_type(4)));
typedef __bf16 bf16x8_t __attribute__((ext_vector_type(8)));
typedef float f32x4_t __attribute__((ext_vector_type(4)));

#define NROWS 8192
#define DDIM  256
#define HDIM  512
#define CHUNK 128
#define NCHUNK (NROWS / CHUNK)   // 64

#define MFMA16(a, b, c) __builtin_amdgcn_mfma_f32_16x16x32_bf16((a), (b), (c), 0, 0, 0)
#define NEG_HALF_LOG2E -0.721347520444482f   // exp(-d2/2) = exp2(d2 * this)

// ---------------------------------------------------------------------------
// prep: fused prep_x + prep_h (one launch).
//  blocks [0,2048):   X f32 -> Xb bf16, sq[i] = sum bf16(x)^2 (f32 accum);
//                     sq MUST use bf16-rounded values so diagonal d2 == 0.
//  blocks [2048,6144): H [8192][512] f32 -> Hbt [512][8192] bf16 (transpose).
// ---------------------------------------------------------------------------
__global__ __launch_bounds__(256) void prep_kernel(
    const float* __restrict__ x, bf16_t* __restrict__ xb,
    float* __restrict__ sq, float* __restrict__ partials,
    const float* __restrict__ h, bf16_t* __restrict__ hbt)
{
    __shared__ float tile[32][33];
    if (blockIdx.x < 2048) {
        const int row  = (blockIdx.x << 2) + (threadIdx.x >> 6); // wave per row
        const int lane = threadIdx.x & 63;
        float4 v = *reinterpret_cast<const float4*>(x + row * DDIM + (lane << 2));
        bf16x4_t b;
        b[0] = (bf16_t)v.x; b[1] = (bf16_t)v.y; b[2] = (bf16_t)v.z; b[3] = (bf16_t)v.w;
        *reinterpret_cast<bf16x4_t*>(xb + row * DDIM + (lane << 2)) = b;
        float f0 = (float)b[0], f1 = (float)b[1], f2 = (float)b[2], f3 = (float)b[3];
        float ss = f0 * f0 + f1 * f1 + f2 * f2 + f3 * f3;
        #pragma unroll
        for (int m = 32; m > 0; m >>= 1) ss += __shfl_xor(ss, m, 64);
        if (lane == 0) sq[row] = ss;
        if (blockIdx.x == 0 && threadIdx.x == 0) { partials[0] = 0.f; partials[1] = 0.f; }
    } else {
        const int bid = blockIdx.x - 2048;
        const int bi = bid & 255;  // i-tile (8192/32)
        const int bh = bid >> 8;   // h-tile (512/32)
        const int i0 = bi << 5, h0 = bh << 5;
        const int c  = threadIdx.x & 31;
        const int rt = threadIdx.x >> 5;  // 0..7
        #pragma unroll
        for (int k = 0; k < 4; ++k) {
            int r = rt + (k << 3);
            tile[r][c] = h[(size_t)(i0 + r) * HDIM + h0 + c];
        }
        __syncthreads();
        #pragma unroll
        for (int k = 0; k < 4; ++k) {
            int hr = rt + (k << 3);
            hbt[(size_t)(h0 + hr) * NROWS + i0 + c] = (bf16_t)tile[c][hr];
        }
    }
}

// ---------------------------------------------------------------------------
// Main fused kernel, two-phase. Grid = 256 blocks (32-row j-tile), 512 thr
// (8 waves). Wave w owns i-slice isub=w (16 rows of each 128-i chunk) and,
// in phase 2, h-slice [w*64, w*64+64).
//
// Phase 1 (barrier-free, hot): scan all 64 chunks; per chunk compute this
//   wave's S fragments (both m, B-frags shared -> half the B traffic),
//   p = exp2(-d2*log2e/2); set mask bit if any p != +0.0. No LDS, no
//   __syncthreads -> no vmcnt(0) drains, loads pipeline freely (R4 was
//   latency-bound at 4600 cyc/chunk from exactly that).
// Phase 2 (rare): OR the 8 wave masks; for each flagged chunk (ascending),
//   recompute S identically, P -> swizzled LDS, barrier, O-GEMM from LDS x
//   Hbt, barrier. Unflagged chunks contributed exactly +0.0 in R4's proven
//   kernel -> output bit-identical.
// Epilogue: p1 = sum invlam*O^2, p2 = sum O*H -> LDS reduce -> 2 atomics.
// ---------------------------------------------------------------------------
__global__ __launch_bounds__(512, 2) void kpca_main(
    const bf16_t* __restrict__ xb, const bf16_t* __restrict__ hbt,
    const float* __restrict__ sq, const float* __restrict__ hmat,
    const float* __restrict__ invlam, float* __restrict__ partials)
{
    __shared__ bf16_t plds[32 * CHUNK];          // 8 KB
    __shared__ unsigned long long wmask[8];
    __shared__ float red[32];

    const int tid  = threadIdx.x;
    const int w    = tid >> 6;
    const int l    = tid & 63;
    const int l15  = l & 15;
    const int lq   = l >> 4;
    const int j0   = blockIdx.x << 5;
    const int isub = w;              // i-slice within a 128-chunk
    const int h0w  = w << 6;         // phase-2 h-slice base

    // Hoisted A fragments, both m (loop-invariant)
    bf16x8_t av[2][8];
    #pragma unroll
    for (int m = 0; m < 2; ++m) {
        const bf16_t* aptr = xb + (size_t)(j0 + (m << 4) + l15) * DDIM + (lq << 3);
        #pragma unroll
        for (int kk = 0; kk < 8; ++kk)
            av[m][kk] = *reinterpret_cast<const bf16x8_t*>(aptr + (kk << 5));
    }
    float sqj[2][4];
    #pragma unroll
    for (int m = 0; m < 2; ++m)
        #pragma unroll
        for (int r = 0; r < 4; ++r)
            sqj[m][r] = sq[j0 + (m << 4) + (lq << 2) + r];

    auto bptr_at = [&](int ic) {
        return xb + (size_t)(ic + (isub << 4) + l15) * DDIM + (lq << 3);
    };

    // one chunk scan: S fragments (both m) + underflow check; no side effects
    auto scan_chunk = [&](const bf16x8_t (&bv)[8], float sqi) -> int {
        f32x4_t s[2][2];
        s[0][0] = s[0][1] = s[1][0] = s[1][1] = (f32x4_t){0.f, 0.f, 0.f, 0.f};
        #pragma unroll
        for (int kk = 0; kk < 8; kk += 2) {
            #pragma unroll
            for (int m = 0; m < 2; ++m) {
                s[m][0] = MFMA16(av[m][kk],     bv[kk],     s[m][0]);
                s[m][1] = MFMA16(av[m][kk + 1], bv[kk + 1], s[m][1]);
            }
        }
        float pm = 0.f;
        #pragma unroll
        for (int m = 0; m < 2; ++m)
            #pragma unroll
            for (int r = 0; r < 4; ++r) {
                float sv = s[m][0][r] + s[m][1][r];
                float d2 = fmaxf(sqj[m][r] + sqi - 2.0f * sv, 0.0f);
                pm = fmaxf(pm, exp2f(d2 * NEG_HALF_LOG2E));
            }
        return __any(pm != 0.0f) ? 1 : 0;
    };

    // ---- phase 1: barrier-free scan, 2-chunk pipelined B stream ----
    unsigned long long mask = 0ull;
    bf16x8_t bvA[8], bvB[8];
    float sqiA, sqiB;
    {
        const bf16_t* p0 = bptr_at(0);
        #pragma unroll
        for (int kk = 0; kk < 8; ++kk)
            bvA[kk] = *reinterpret_cast<const bf16x8_t*>(p0 + (kk << 5));
        sqiA = sq[(isub << 4) + l15];
    }
    for (int c = 0; c < NCHUNK; c += 2) {
        const bf16_t* pB = bptr_at((c + 1) * CHUNK);
        #pragma unroll
        for (int kk = 0; kk < 8; ++kk)
            bvB[kk] = *reinterpret_cast<const bf16x8_t*>(pB + (kk << 5));
        sqiB = sq[(c + 1) * CHUNK + (isub << 4) + l15];
        if (scan_chunk(bvA, sqiA)) mask |= (1ull << c);
        const int cn = (c + 2) & (NCHUNK - 1);          // wrap: harmless
        const bf16_t* pA = bptr_at(cn * CHUNK);
        #pragma unroll
        for (int kk = 0; kk < 8; ++kk)
            bvA[kk] = *reinterpret_cast<const bf16x8_t*>(pA + (kk << 5));
        sqiA = sq[cn * CHUNK + (isub << 4) + l15];
        if (scan_chunk(bvB, sqiB)) mask |= (1ull << (c + 1));
    }

    wmask[w] = mask;
    __syncthreads();
    unsigned long long full = 0ull;
    #pragma unroll
    for (int i = 0; i < 8; ++i) full |= wmask[i];

    // ---- phase 2: process flagged chunks (ascending ic, bit-same as R4) ----
    f32x4_t acc[2][4];
    #pragma unroll
    for (int a = 0; a < 2; ++a)
        #pragma unroll
        for (int b = 0; b < 4; ++b)
            acc[a][b] = (f32x4_t){0.f, 0.f, 0.f, 0.f};

    while (full) {
        const int c = __ffsll(full) - 1;
        full &= full - 1ull;
        const int ic = c * CHUNK;

        // recompute S for this wave's slice (identical math to scan)
        bf16x8_t bv[8];
        const bf16_t* pb = bptr_at(ic);
        #pragma unroll
        for (int kk = 0; kk < 8; ++kk)
            bv[kk] = *reinterpret_cast<const bf16x8_t*>(pb + (kk << 5));
        const float sqi = sq[ic + (isub << 4) + l15];
        f32x4_t s[2][2];
        s[0][0] = s[0][1] = s[1][0] = s[1][1] = (f32x4_t){0.f, 0.f, 0.f, 0.f};
        #pragma unroll
        for (int kk = 0; kk < 8; kk += 2) {
            #pragma unroll
            for (int m = 0; m < 2; ++m) {
                s[m][0] = MFMA16(av[m][kk],     bv[kk],     s[m][0]);
                s[m][1] = MFMA16(av[m][kk + 1], bv[kk + 1], s[m][1]);
            }
        }
        const int il = (isub << 4) + l15;
        #pragma unroll
        for (int m = 0; m < 2; ++m)
            #pragma unroll
            for (int r = 0; r < 4; ++r) {
                float sv = s[m][0][r] + s[m][1][r];
                float d2 = fmaxf(sqj[m][r] + sqi - 2.0f * sv, 0.0f);
                float p  = exp2f(d2 * NEG_HALF_LOG2E);
                int jl = (m << 4) + (lq << 2) + r;
                plds[(jl << 7) + (il ^ ((jl & 7) << 3))] = (bf16_t)p;
            }
        __syncthreads();

        // O-GEMM: O[32j][64h slice] += P[32][128] @ Hbt-slice
        #pragma unroll
        for (int kf = 0; kf < 4; ++kf) {
            bf16x8_t pa[2];
            #pragma unroll
            for (int mf = 0; mf < 2; ++mf) {
                int jl = (mf << 4) + l15;
                int ik = (kf << 5) + (lq << 3);
                pa[mf] = *reinterpret_cast<const bf16x8_t*>(
                    &plds[(jl << 7) + (ik ^ ((jl & 7) << 3))]);
            }
            #pragma unroll
            for (int nf = 0; nf < 4; ++nf) {
                const bf16x8_t hv = *reinterpret_cast<const bf16x8_t*>(
                    hbt + (size_t)(h0w + (nf << 4) + l15) * NROWS
                        + ic + (kf << 5) + (lq << 3));
                acc[0][nf] = MFMA16(pa[0], hv, acc[0][nf]);
                acc[1][nf] = MFMA16(pa[1], hv, acc[1][nf]);
            }
        }
        __syncthreads();   // protect plds before next flagged chunk
    }

    // ---- epilogue: loss partials ----
    float p1 = 0.f, p2 = 0.f;
    #pragma unroll
    for (int mf = 0; mf < 2; ++mf) {
        #pragma unroll
        for (int nf = 0; nf < 4; ++nf) {
            const int hh = h0w + (nf << 4) + l15;
            const float lam = invlam[hh];
            #pragma unroll
            for (int r = 0; r < 4; ++r) {
                const int j = j0 + (mf << 4) + (lq << 2) + r;
                const float v = acc[mf][nf][r];
                p1 = fmaf(lam * v, v, p1);
                p2 = fmaf(v, hmat[(size_t)j * HDIM + hh], p2);
            }
        }
    }
    #pragma unroll
    for (int sft = 32; sft > 0; sft >>= 1) {
        p1 += __shfl_xor(p1, sft, 64);
        p2 += __shfl_xor(p2, sft, 64);
    }
    if (l == 0) { red[w] = p1; red[16 + w] = p2; }
    __syncthreads();
    if (tid == 0) {
        float a = 0.f, b = 0.f;
        #pragma unroll
        for (int i = 0; i < 8; ++i) { a += red[i]; b += red[16 + i]; }
        atomicAdd(&partials[0], a);
        atomicAdd(&partials[1], b);
    }
}

// ---------------------------------------------------------------------------
// finalize: s = loss1 + loss2, out = s + 0.05*s^2
// ---------------------------------------------------------------------------
__global__ void finalize_kernel(const float* __restrict__ partials,
                                float* __restrict__ out)
{
    if (threadIdx.x == 0) {
        float s = -0.5f * partials[0] + 0.5f * partials[1];
        out[0] = s + 0.05f * s * s;
    }
}

// ---------------------------------------------------------------------------
// ws layout: Xb bf16[8192][256] (4MB) | Hbt bf16[512][8192] (8MB)
//            | sq f32[8192] (32KB) | partials f32[2]        (~12.03 MB total)
// ---------------------------------------------------------------------------
extern "C" void kernel_launch(void* const* d_in, const int* in_sizes, int n_in,
                              void* d_out, int out_size, void* d_ws, size_t ws_size,
                              hipStream_t stream)
{
    const float* x      = (const float*)d_in[0];
    const float* h      = (const float*)d_in[1];
    const float* invlam = (const float*)d_in[2];
    float* out = (float*)d_out;

    char* wsb = (char*)d_ws;
    bf16_t* xb  = (bf16_t*)wsb;
    bf16_t* hbt = (bf16_t*)(wsb + (size_t)NROWS * DDIM * 2);
    float*  sq  = (float*)(wsb + (size_t)NROWS * DDIM * 2 + (size_t)HDIM * NROWS * 2);
    float*  partials = sq + NROWS;

    hipLaunchKernelGGL(prep_kernel, dim3(2048 + 4096), dim3(256), 0, stream,
                       x, xb, sq, partials, h, hbt);
    hipLaunchKernelGGL(kpca_main, dim3(NROWS / 32), dim3(512), 0, stream,
                       xb, hbt, sq, h, invlam, partials);
    hipLaunchKernelGGL(finalize_kernel, dim3(1), dim3(64), 0, stream,
                       partials, out);
}